// Round 2
// baseline (12403.461 us; speedup 1.0000x reference)
//
#include <hip/hip_runtime.h>

typedef __attribute__((ext_vector_type(4))) float f4;

// ---------------------------------------------------------------------------
// Simple fp32 GEMM over one batch slice: C[2048][N] = A[2048][K] @ W[K][N] + bias
// 64x64 block tile, BK=16, 256 threads, 4x4 micro-tile.
// MODE 0: write per-head q/k layout  out[(n>>6)*2048*64 + s*64 + (n&63)]   (N=1024)
// MODE 2: write per-head v layout    out[(n>>5)*2048*32 + s*32 + (n&31)]   (N=512)
// MODE 3: write row-major            out[s*1024 + n]                        (N=1024)
// ---------------------------------------------------------------------------
template <int MODE>
__global__ __launch_bounds__(256) void sgemm(
    const float* __restrict__ A, const float* __restrict__ W,
    const float* __restrict__ bias, float* __restrict__ outp,
    const int N, const int K) {
  __shared__ float As[64][17];
  __shared__ float Bs[16][65];
  const int t = threadIdx.x;
  const int tx = t & 15, ty = t >> 4;
  const int bn = blockIdx.x * 64, bm = blockIdx.y * 64;
  float acc[4][4] = {};

  for (int kt = 0; kt < K; kt += 16) {
#pragma unroll
    for (int i = 0; i < 4; ++i) {  // stage A: 64 rows x 16 k
      const int idx = t + i * 256;
      const int r = idx >> 4, c = idx & 15;
      As[r][c] = A[(size_t)(bm + r) * K + kt + c];
    }
#pragma unroll
    for (int i = 0; i < 4; ++i) {  // stage B: 16 k x 64 cols
      const int idx = t + i * 256;
      const int r = idx >> 6, c = idx & 63;
      Bs[r][c] = W[(size_t)(kt + r) * N + bn + c];
    }
    __syncthreads();
#pragma unroll
    for (int kk = 0; kk < 16; ++kk) {
      float a[4], bv[4];
#pragma unroll
      for (int i = 0; i < 4; ++i) a[i] = As[ty * 4 + i][kk];
#pragma unroll
      for (int j = 0; j < 4; ++j) bv[j] = Bs[kk][tx * 4 + j];
#pragma unroll
      for (int i = 0; i < 4; ++i)
#pragma unroll
        for (int j = 0; j < 4; ++j) acc[i][j] = fmaf(a[i], bv[j], acc[i][j]);
    }
    __syncthreads();
  }

#pragma unroll
  for (int i = 0; i < 4; ++i) {
    const int s = bm + ty * 4 + i;
#pragma unroll
    for (int j = 0; j < 4; ++j) {
      const int n = bn + tx * 4 + j;
      const float g = acc[i][j] + bias[n];
      if (MODE == 0) {
        outp[((size_t)(n >> 6) * 2048 + s) * 64 + (n & 63)] = g;
      } else if (MODE == 2) {
        outp[((size_t)(n >> 5) * 2048 + s) * 32 + (n & 31)] = g;
      } else {
        outp[(size_t)s * 1024 + n] = g;
      }
    }
  }
}

// ---------------------------------------------------------------------------
// Naive causal attention for one batch slice, fp32, no LDS.
// qf/kf: [16][2048][64]; vf: [16][2048][32]; att: [2048][512] (cols = h*32+r).
// One thread per q-row. Two passes: exact row max, then exp-sum + PV.
// ---------------------------------------------------------------------------
__global__ __launch_bounds__(256) void attn_naive(
    const float* __restrict__ qf, const float* __restrict__ kf,
    const float* __restrict__ vf, float* __restrict__ att) {
  const int h = blockIdx.x;                         // [0,16)
  const int row = blockIdx.y * 256 + threadIdx.x;   // [0,2048)

  float qr[64];
  {
    const float* q = qf + ((size_t)h * 2048 + row) * 64;
#pragma unroll
    for (int i = 0; i < 16; ++i) {
      const f4 v = *(const f4*)(q + i * 4);
      qr[i * 4 + 0] = v.x; qr[i * 4 + 1] = v.y;
      qr[i * 4 + 2] = v.z; qr[i * 4 + 3] = v.w;
    }
  }
  const float* kb = kf + (size_t)h * 2048 * 64;
  const float* vb = vf + (size_t)h * 2048 * 32;

  // pass 1: exact max over valid keys
  float m = -3.0e38f;
  for (int k = 0; k <= row; ++k) {
    const float* kr = kb + (size_t)k * 64;
    float dot = 0.f;
#pragma unroll
    for (int i = 0; i < 16; ++i) {
      const f4 v = *(const f4*)(kr + i * 4);
      dot = fmaf(qr[i * 4 + 0], v.x, dot);
      dot = fmaf(qr[i * 4 + 1], v.y, dot);
      dot = fmaf(qr[i * 4 + 2], v.z, dot);
      dot = fmaf(qr[i * 4 + 3], v.w, dot);
    }
    m = fmaxf(m, dot * 0.125f);
  }

  // pass 2: denominator + PV accumulate
  float o[32];
#pragma unroll
  for (int r = 0; r < 32; ++r) o[r] = 0.f;
  float l = 0.f;
  for (int k = 0; k <= row; ++k) {
    const float* kr = kb + (size_t)k * 64;
    float dot = 0.f;
#pragma unroll
    for (int i = 0; i < 16; ++i) {
      const f4 v = *(const f4*)(kr + i * 4);
      dot = fmaf(qr[i * 4 + 0], v.x, dot);
      dot = fmaf(qr[i * 4 + 1], v.y, dot);
      dot = fmaf(qr[i * 4 + 2], v.z, dot);
      dot = fmaf(qr[i * 4 + 3], v.w, dot);
    }
    const float p = __expf(dot * 0.125f - m);
    l += p;
    const float* vr = vb + (size_t)k * 32;
#pragma unroll
    for (int r8 = 0; r8 < 8; ++r8) {
      const f4 v = *(const f4*)(vr + r8 * 4);
      o[r8 * 4 + 0] = fmaf(p, v.x, o[r8 * 4 + 0]);
      o[r8 * 4 + 1] = fmaf(p, v.y, o[r8 * 4 + 1]);
      o[r8 * 4 + 2] = fmaf(p, v.z, o[r8 * 4 + 2]);
      o[r8 * 4 + 3] = fmaf(p, v.w, o[r8 * 4 + 3]);
    }
  }

  const float inv = 1.f / l;  // diagonal always valid -> l >= 1
  float* op = att + (size_t)row * 512 + h * 32;
#pragma unroll
  for (int r8 = 0; r8 < 8; ++r8) {
    f4 v;
    v.x = o[r8 * 4 + 0] * inv;
    v.y = o[r8 * 4 + 1] * inv;
    v.z = o[r8 * 4 + 2] * inv;
    v.w = o[r8 * 4 + 3] * inv;
    *(f4*)(op + r8 * 4) = v;
  }
}

// ---------------------------------------------------------------------------
extern "C" void kernel_launch(void* const* d_in, const int* in_sizes, int n_in,
                              void* d_out, int out_size, void* d_ws, size_t ws_size,
                              hipStream_t stream) {
  const float* hs = (const float*)d_in[0];
  const float* qw = (const float*)d_in[1];
  const float* qb = (const float*)d_in[2];
  const float* kw = (const float*)d_in[3];
  const float* kb = (const float*)d_in[4];
  const float* vw = (const float*)d_in[5];
  const float* vb = (const float*)d_in[6];
  const float* ow = (const float*)d_in[7];
  const float* ob = (const float*)d_in[8];
  float* out = (float*)d_out;

  // Scratch (per-batch, reused): 24 MB total.
  char* ws = (char*)d_ws;
  float* qf = (float*)(ws);                         //  8 MB [16][2048][64]
  float* kf = (float*)(ws + ((size_t)8 << 20));     //  8 MB [16][2048][64]
  float* vf = (float*)(ws + ((size_t)16 << 20));    //  4 MB [16][2048][32]
  float* att = (float*)(ws + ((size_t)20 << 20));   //  4 MB [2048][512]

  for (int b = 0; b < 4; ++b) {
    const float* hs_b = hs + (size_t)b * 2048 * 1024;
    float* out_b = out + (size_t)b * 2048 * 1024;
    sgemm<0><<<dim3(16, 32), 256, 0, stream>>>(hs_b, qw, qb, qf, 1024, 1024);
    sgemm<0><<<dim3(16, 32), 256, 0, stream>>>(hs_b, kw, kb, kf, 1024, 1024);
    sgemm<2><<<dim3(8, 32), 256, 0, stream>>>(hs_b, vw, vb, vf, 512, 1024);
    attn_naive<<<dim3(16, 8), 256, 0, stream>>>(qf, kf, vf, att);
    sgemm<3><<<dim3(16, 32), 256, 0, stream>>>(att, ow, ob, out_b, 1024, 512);
  }
}

// Round 3
// 1883.915 us; speedup vs baseline: 6.5839x; 6.5839x over previous
//
#include <hip/hip_runtime.h>

typedef __attribute__((ext_vector_type(4))) float f4;

// ---------------------------------------------------------------------------
// fp32 GEMM: C[M][N] = A[M][K] @ W[K][N] + bias
// 64x64 block tile, BK=16, 256 threads, 4x4 micro-tile.
// MODE 0: per-head q/k layout  out[((n>>6)*SROWS + s)*64 + (n&63)]
// MODE 2: per-head v layout    out[((n>>5)*SROWS + s)*32 + (n&31)]
// MODE 3: row-major            out[s*N + n]
// For MODE 0/2 with full-batch M=8192: head index folds b: hh = (m>>11)*16+(n>>6).
// We handle that by passing SROWS=2048 and computing b from m.
// ---------------------------------------------------------------------------
template <int MODE>
__global__ __launch_bounds__(256) void sgemm(
    const float* __restrict__ A, const float* __restrict__ W,
    const float* __restrict__ bias, float* __restrict__ outp,
    const int N, const int K) {
  __shared__ float As[64][17];
  __shared__ float Bs[16][65];
  const int t = threadIdx.x;
  const int tx = t & 15, ty = t >> 4;
  const int bn = blockIdx.x * 64, bm = blockIdx.y * 64;
  float acc[4][4] = {};

  for (int kt = 0; kt < K; kt += 16) {
#pragma unroll
    for (int i = 0; i < 4; ++i) {  // stage A: 64 rows x 16 k
      const int idx = t + i * 256;
      const int r = idx >> 4, c = idx & 15;
      As[r][c] = A[(size_t)(bm + r) * K + kt + c];
    }
#pragma unroll
    for (int i = 0; i < 4; ++i) {  // stage B: 16 k x 64 cols
      const int idx = t + i * 256;
      const int r = idx >> 6, c = idx & 63;
      Bs[r][c] = W[(size_t)(kt + r) * N + bn + c];
    }
    __syncthreads();
#pragma unroll
    for (int kk = 0; kk < 16; ++kk) {
      float a[4], bv[4];
#pragma unroll
      for (int i = 0; i < 4; ++i) a[i] = As[ty * 4 + i][kk];
#pragma unroll
      for (int j = 0; j < 4; ++j) bv[j] = Bs[kk][tx * 4 + j];
#pragma unroll
      for (int i = 0; i < 4; ++i)
#pragma unroll
        for (int j = 0; j < 4; ++j) acc[i][j] = fmaf(a[i], bv[j], acc[i][j]);
    }
    __syncthreads();
  }

#pragma unroll
  for (int i = 0; i < 4; ++i) {
    const int mrow = bm + ty * 4 + i;
    const int bb = mrow >> 11, ss = mrow & 2047;  // batch, seq within batch
#pragma unroll
    for (int j = 0; j < 4; ++j) {
      const int n = bn + tx * 4 + j;
      const float g = acc[i][j] + bias[n];
      if (MODE == 0) {  // [BH][2048][64]
        outp[((size_t)(bb * 16 + (n >> 6)) * 2048 + ss) * 64 + (n & 63)] = g;
      } else if (MODE == 2) {  // [BH][2048][32]
        outp[((size_t)(bb * 16 + (n >> 5)) * 2048 + ss) * 32 + (n & 31)] = g;
      } else {  // row-major [M][N]
        outp[(size_t)mrow * N + n] = g;
      }
    }
  }
}

// ---------------------------------------------------------------------------
// Single-pass causal flash attention, fp32, K/V tiles in LDS.
// qf/kf: [NBH][2048][64]; vf: [NBH][2048][32]; att: [(b*2048+s)*512 + h*32+r]
// One thread per q-row; 256 q-rows per block; TK=64 keys per tile.
// Heavy q-blocks launch first (load balance); wave-uniform skip of masked
// chunks. NBH=64: full batch. NBH=16: single batch slice (b==0 in att index).
// ---------------------------------------------------------------------------
template <int NBH>
__global__ __launch_bounds__(256) void attn_flash(
    const float* __restrict__ qf, const float* __restrict__ kf,
    const float* __restrict__ vf, float* __restrict__ att) {
  __shared__ float Ks[64][64];  // 16 KB
  __shared__ float Vs[64][32];  //  8 KB
  const int id = blockIdx.x;
  const int bh = id % NBH;
  const int qblk = 7 - (id / NBH);  // heavy blocks first
  const int t = threadIdx.x;
  const int row = qblk * 256 + t;
  const int b = bh >> 4, h = bh & 15;

  float qr[64];
  {
    const float* qp = qf + ((size_t)bh * 2048 + row) * 64;
#pragma unroll
    for (int i = 0; i < 16; ++i) {
      const f4 v = *(const f4*)(qp + i * 4);
      qr[i * 4 + 0] = v.x; qr[i * 4 + 1] = v.y;
      qr[i * 4 + 2] = v.z; qr[i * 4 + 3] = v.w;
    }
  }
  float o[32];
#pragma unroll
  for (int r = 0; r < 32; ++r) o[r] = 0.f;
  float m = -3.0e38f, l = 0.f;

  const int wrowmax = qblk * 256 + (t | 63);  // wave-uniform causal bound
  const int ntiles = qblk * 4 + 4;
  for (int kt = 0; kt < ntiles; ++kt) {
    const int kbase = kt * 64;
    __syncthreads();
#pragma unroll
    for (int i = 0; i < 4; ++i) {  // stage K tile 64x64
      const int f = t + i * 256;
      const int r = f >> 4, c = f & 15;
      *(f4*)&Ks[r][c * 4] =
          *(const f4*)(kf + ((size_t)bh * 2048 + kbase + r) * 64 + c * 4);
    }
#pragma unroll
    for (int i = 0; i < 2; ++i) {  // stage V tile 64x32
      const int f = t + i * 256;
      const int r = f >> 3, c = f & 7;
      *(f4*)&Vs[r][c * 4] =
          *(const f4*)(vf + ((size_t)bh * 2048 + kbase + r) * 32 + c * 4);
    }
    __syncthreads();

#pragma unroll
    for (int ch = 0; ch < 4; ++ch) {
      if (kbase + ch * 16 > wrowmax) break;  // wave-uniform: fully masked
      float s[16];
      float cmax = -3.0e38f;
#pragma unroll
      for (int kk = 0; kk < 16; ++kk) {
        const int krow = ch * 16 + kk;
        float dot = 0.f;
#pragma unroll
        for (int i = 0; i < 16; ++i) {
          const f4 v = *(const f4*)&Ks[krow][i * 4];
          dot = fmaf(qr[i * 4 + 0], v.x, dot);
          dot = fmaf(qr[i * 4 + 1], v.y, dot);
          dot = fmaf(qr[i * 4 + 2], v.z, dot);
          dot = fmaf(qr[i * 4 + 3], v.w, dot);
        }
        s[kk] = dot * 0.125f;
        cmax = (kbase + krow <= row) ? fmaxf(cmax, s[kk]) : cmax;
      }
      const float mnew = fmaxf(m, cmax);
      const float corr = __expf(m - mnew);
      l *= corr;
      m = mnew;
#pragma unroll
      for (int r = 0; r < 32; ++r) o[r] *= corr;
#pragma unroll
      for (int kk = 0; kk < 16; ++kk) {
        const int krow = ch * 16 + kk;
        const float p = (kbase + krow <= row) ? __expf(s[kk] - m) : 0.f;
        l += p;
#pragma unroll
        for (int i = 0; i < 8; ++i) {
          const f4 v = *(const f4*)&Vs[krow][i * 4];
          o[i * 4 + 0] = fmaf(p, v.x, o[i * 4 + 0]);
          o[i * 4 + 1] = fmaf(p, v.y, o[i * 4 + 1]);
          o[i * 4 + 2] = fmaf(p, v.z, o[i * 4 + 2]);
          o[i * 4 + 3] = fmaf(p, v.w, o[i * 4 + 3]);
        }
      }
    }
  }

  const float inv = 1.f / l;  // diagonal key always valid -> l >= ~1
  float* op = att + ((size_t)b * 2048 + row) * 512 + h * 32;
#pragma unroll
  for (int r8 = 0; r8 < 8; ++r8) {
    f4 v;
    v.x = o[r8 * 4 + 0] * inv;
    v.y = o[r8 * 4 + 1] * inv;
    v.z = o[r8 * 4 + 2] * inv;
    v.w = o[r8 * 4 + 3] * inv;
    *(f4*)(op + r8 * 4) = v;
  }
}

// ---------------------------------------------------------------------------
extern "C" void kernel_launch(void* const* d_in, const int* in_sizes, int n_in,
                              void* d_out, int out_size, void* d_ws, size_t ws_size,
                              hipStream_t stream) {
  const float* hs = (const float*)d_in[0];
  const float* qw = (const float*)d_in[1];
  const float* qb = (const float*)d_in[2];
  const float* kw = (const float*)d_in[3];
  const float* kb = (const float*)d_in[4];
  const float* vw = (const float*)d_in[5];
  const float* vb = (const float*)d_in[6];
  const float* ow = (const float*)d_in[7];
  const float* ob = (const float*)d_in[8];
  float* out = (float*)d_out;
  char* ws = (char*)d_ws;

  if (ws_size >= ((size_t)96 << 20)) {
    // Full-batch path: qf 32MB | kf 32MB | vf 16MB | att 16MB
    float* qf = (float*)(ws);
    float* kf = (float*)(ws + ((size_t)32 << 20));
    float* vf = (float*)(ws + ((size_t)64 << 20));
    float* att = (float*)(ws + ((size_t)80 << 20));
    sgemm<0><<<dim3(16, 128), 256, 0, stream>>>(hs, qw, qb, qf, 1024, 1024);
    sgemm<0><<<dim3(16, 128), 256, 0, stream>>>(hs, kw, kb, kf, 1024, 1024);
    sgemm<2><<<dim3(8, 128), 256, 0, stream>>>(hs, vw, vb, vf, 512, 1024);
    attn_flash<64><<<dim3(512), 256, 0, stream>>>(qf, kf, vf, att);
    sgemm<3><<<dim3(16, 128), 256, 0, stream>>>(att, ow, ob, out, 1024, 512);
  } else {
    // Per-batch fallback: qf 8MB | kf 8MB | vf 4MB | att 4MB  (24 MB)
    float* qf = (float*)(ws);
    float* kf = (float*)(ws + ((size_t)8 << 20));
    float* vf = (float*)(ws + ((size_t)16 << 20));
    float* att = (float*)(ws + ((size_t)20 << 20));
    for (int b = 0; b < 4; ++b) {
      const float* hs_b = hs + (size_t)b * 2048 * 1024;
      float* out_b = out + (size_t)b * 2048 * 1024;
      sgemm<0><<<dim3(16, 32), 256, 0, stream>>>(hs_b, qw, qb, qf, 1024, 1024);
      sgemm<0><<<dim3(16, 32), 256, 0, stream>>>(hs_b, kw, kb, kf, 1024, 1024);
      sgemm<2><<<dim3(8, 32), 256, 0, stream>>>(hs_b, vw, vb, vf, 512, 1024);
      attn_flash<16><<<dim3(128), 256, 0, stream>>>(qf, kf, vf, att);
      sgemm<3><<<dim3(16, 32), 256, 0, stream>>>(att, ow, ob, out_b, 1024, 512);
    }
  }
}

// Round 4
// 1041.047 us; speedup vs baseline: 11.9144x; 1.8096x over previous
//
#include <hip/hip_runtime.h>

typedef _Float16 f16;
typedef __attribute__((ext_vector_type(4))) float f4;
typedef __attribute__((ext_vector_type(4))) _Float16 h4;
typedef __attribute__((ext_vector_type(8))) _Float16 h8;
typedef __attribute__((ext_vector_type(4))) float f32x4;

// ---------------------------------------------------------------------------
// Straight cast fp32 -> f16, 4 elems/thread, grid-stride. n4 = n/4.
// ---------------------------------------------------------------------------
__global__ __launch_bounds__(256) void cast_f16(
    const float* __restrict__ in, f16* __restrict__ out, int n4) {
  for (int i = blockIdx.x * 256 + threadIdx.x; i < n4; i += gridDim.x * 256) {
    const f4 v = ((const f4*)in)[i];
    h4 h;
    h.x = (f16)v.x; h.y = (f16)v.y; h.z = (f16)v.z; h.w = (f16)v.w;
    ((h4*)out)[i] = h;
  }
}

// ---------------------------------------------------------------------------
// Transpose + cast: in [R][C] fp32 -> out [C][R] f16. 32x32 LDS tile.
// ---------------------------------------------------------------------------
__global__ __launch_bounds__(256) void transpose_cast(
    const float* __restrict__ in, f16* __restrict__ out, int R, int C) {
  __shared__ float tile[32][33];
  const int t = threadIdx.x, tx = t & 31, ty = t >> 5;
  const int bc = blockIdx.x * 32, br = blockIdx.y * 32;
#pragma unroll
  for (int i = 0; i < 4; ++i)
    tile[ty + i * 8][tx] = in[(size_t)(br + ty + i * 8) * C + bc + tx];
  __syncthreads();
#pragma unroll
  for (int i = 0; i < 4; ++i)
    out[(size_t)(bc + ty + i * 8) * R + br + tx] = (f16)tile[tx][ty + i * 8];
}

// ---------------------------------------------------------------------------
// f16 MFMA GEMM: C[M][N] = A[M][K] @ B[K][N] + bias, with B given TRANSPOSED
// (Bt [N][K], rows contiguous in K — same staging as A).
// 128x128 tile, BK=32, 256 threads = 4 waves, each wave 64x64 (4x4 frags of
// 16x16x32). LDS rows stride 40 f16 (80 B, 16B-aligned, depow2 banks).
// Fragment map: lane l: A[row=l&15][k=(l>>4)*8+e], B[k][col=l&15];
// D reg j -> row=(l>>4)*4+j, col=l&15  [m89-verified].
// MODE 0: f16 out [(bb*16+(n>>6))*2048+ss]*64+(n&63)   (q/k heads)
// MODE 2: f16 out [(bb*16+(n>>5))*2048+ss]*32+(n&31)   (v heads)
// MODE 3: f32 out row-major [M][N]
// ---------------------------------------------------------------------------
typedef __attribute__((ext_vector_type(4))) unsigned int u4;

template <int MODE>
__global__ __launch_bounds__(256) void hgemm(
    const f16* __restrict__ A, const f16* __restrict__ Bt,
    const float* __restrict__ bias, void* __restrict__ outp,
    const int N, const int K) {
  __shared__ f16 As[128 * 40];
  __shared__ f16 Bs[128 * 40];
  const int t = threadIdx.x;
  const int lane = t & 63, wave = t >> 6;
  const int wr = wave >> 1, wc = wave & 1;
  const int lrow = lane & 15, lk = lane >> 4;  // fragment row/col, k-chunk
  const int bm = blockIdx.y * 128, bn = blockIdx.x * 128;

  f32x4 acc[4][4];
#pragma unroll
  for (int i = 0; i < 4; ++i)
#pragma unroll
    for (int j = 0; j < 4; ++j) acc[i][j] = (f32x4)0.f;

  for (int kt = 0; kt < K; kt += 32) {
#pragma unroll
    for (int i = 0; i < 2; ++i) {  // stage: 128 rows x 32 f16 each matrix
      const int ch = t + i * 256;
      const int row = ch >> 2, part = ch & 3;
      *(u4*)&As[row * 40 + part * 8] =
          *(const u4*)(A + (size_t)(bm + row) * K + kt + part * 8);
      *(u4*)&Bs[row * 40 + part * 8] =
          *(const u4*)(Bt + (size_t)(bn + row) * K + kt + part * 8);
    }
    __syncthreads();
    h8 af[4], bf[4];
#pragma unroll
    for (int f = 0; f < 4; ++f) {
      af[f] = *(const h8*)&As[(wr * 64 + f * 16 + lrow) * 40 + lk * 8];
      bf[f] = *(const h8*)&Bs[(wc * 64 + f * 16 + lrow) * 40 + lk * 8];
    }
#pragma unroll
    for (int i = 0; i < 4; ++i)
#pragma unroll
      for (int j = 0; j < 4; ++j)
        acc[i][j] = __builtin_amdgcn_mfma_f32_16x16x32_f16(af[i], bf[j], acc[i][j], 0, 0, 0);
    __syncthreads();
  }

#pragma unroll
  for (int fi = 0; fi < 4; ++fi) {
#pragma unroll
    for (int j = 0; j < 4; ++j) {
      const int grow = bm + wr * 64 + fi * 16 + lk * 4 + j;
      const int bb = grow >> 11, ss = grow & 2047;
#pragma unroll
      for (int fj = 0; fj < 4; ++fj) {
        const int gcol = bn + wc * 64 + fj * 16 + lrow;
        const float g = acc[fi][fj][j] + bias[gcol];
        if (MODE == 0) {
          ((f16*)outp)[((size_t)(bb * 16 + (gcol >> 6)) * 2048 + ss) * 64 + (gcol & 63)] = (f16)g;
        } else if (MODE == 2) {
          ((f16*)outp)[((size_t)(bb * 16 + (gcol >> 5)) * 2048 + ss) * 32 + (gcol & 31)] = (f16)g;
        } else {
          ((float*)outp)[(size_t)grow * N + gcol] = g;
        }
      }
    }
  }
}

// ---------------------------------------------------------------------------
// Single-pass causal flash attention. Inputs f16 (converted to fp32 during
// staging); all math and LDS layout identical to the verified round-3 kernel.
// qf/kf: [64][2048][64] f16; vf: [64][2048][32] f16; att fp32 [8192][512].
// ---------------------------------------------------------------------------
__global__ __launch_bounds__(256) void attn_flash(
    const f16* __restrict__ qf, const f16* __restrict__ kf,
    const f16* __restrict__ vf, float* __restrict__ att) {
  __shared__ float Ks[64][64];  // 16 KB
  __shared__ float Vs[64][32];  //  8 KB
  const int id = blockIdx.x;
  const int bh = id % 64;
  const int qblk = 7 - (id / 64);  // heavy blocks first
  const int t = threadIdx.x;
  const int row = qblk * 256 + t;
  const int b = bh >> 4, h = bh & 15;

  float qr[64];
  {
    const h8* qp = (const h8*)(qf + ((size_t)bh * 2048 + row) * 64);
#pragma unroll
    for (int c = 0; c < 8; ++c) {
      const h8 hv = qp[c];
#pragma unroll
      for (int e = 0; e < 8; ++e) qr[c * 8 + e] = (float)hv[e];
    }
  }
  float o[32];
#pragma unroll
  for (int r = 0; r < 32; ++r) o[r] = 0.f;
  float m = -3.0e38f, l = 0.f;

  const int wrowmax = qblk * 256 + (t | 63);  // wave-uniform causal bound
  const int ntiles = qblk * 4 + 4;
  for (int kt = 0; kt < ntiles; ++kt) {
    const int kbase = kt * 64;
    __syncthreads();
#pragma unroll
    for (int i = 0; i < 2; ++i) {  // stage K tile 64x64 (f16 -> f32)
      const int ch = t + i * 256;
      const int r = ch >> 3, c8 = ch & 7;
      const h8 hv = *(const h8*)(kf + ((size_t)bh * 2048 + kbase + r) * 64 + c8 * 8);
      f4 lo, hi;
      lo.x = (float)hv[0]; lo.y = (float)hv[1]; lo.z = (float)hv[2]; lo.w = (float)hv[3];
      hi.x = (float)hv[4]; hi.y = (float)hv[5]; hi.z = (float)hv[6]; hi.w = (float)hv[7];
      *(f4*)&Ks[r][c8 * 8] = lo;
      *(f4*)&Ks[r][c8 * 8 + 4] = hi;
    }
#pragma unroll
    for (int i = 0; i < 2; ++i) {  // stage V tile 64x32 (f16 -> f32)
      const int ch = t + i * 256;
      const int r = ch >> 2, c8 = ch & 3;
      const h8 hv = *(const h8*)(vf + ((size_t)bh * 2048 + kbase + r) * 32 + c8 * 8);
      f4 lo, hi;
      lo.x = (float)hv[0]; lo.y = (float)hv[1]; lo.z = (float)hv[2]; lo.w = (float)hv[3];
      hi.x = (float)hv[4]; hi.y = (float)hv[5]; hi.z = (float)hv[6]; hi.w = (float)hv[7];
      *(f4*)&Vs[r][c8 * 8] = lo;
      *(f4*)&Vs[r][c8 * 8 + 4] = hi;
    }
    __syncthreads();

#pragma unroll
    for (int ch = 0; ch < 4; ++ch) {
      if (kbase + ch * 16 > wrowmax) break;  // wave-uniform: fully masked
      float s[16];
      float cmax = -3.0e38f;
#pragma unroll
      for (int kk = 0; kk < 16; ++kk) {
        const int krow = ch * 16 + kk;
        float dot = 0.f;
#pragma unroll
        for (int i = 0; i < 16; ++i) {
          const f4 v = *(const f4*)&Ks[krow][i * 4];
          dot = fmaf(qr[i * 4 + 0], v.x, dot);
          dot = fmaf(qr[i * 4 + 1], v.y, dot);
          dot = fmaf(qr[i * 4 + 2], v.z, dot);
          dot = fmaf(qr[i * 4 + 3], v.w, dot);
        }
        s[kk] = dot * 0.125f;
        cmax = (kbase + krow <= row) ? fmaxf(cmax, s[kk]) : cmax;
      }
      const float mnew = fmaxf(m, cmax);
      const float corr = __expf(m - mnew);
      l *= corr;
      m = mnew;
#pragma unroll
      for (int r = 0; r < 32; ++r) o[r] *= corr;
#pragma unroll
      for (int kk = 0; kk < 16; ++kk) {
        const int krow = ch * 16 + kk;
        const float p = (kbase + krow <= row) ? __expf(s[kk] - m) : 0.f;
        l += p;
#pragma unroll
        for (int i = 0; i < 8; ++i) {
          const f4 v = *(const f4*)&Vs[krow][i * 4];
          o[i * 4 + 0] = fmaf(p, v.x, o[i * 4 + 0]);
          o[i * 4 + 1] = fmaf(p, v.y, o[i * 4 + 1]);
          o[i * 4 + 2] = fmaf(p, v.z, o[i * 4 + 2]);
          o[i * 4 + 3] = fmaf(p, v.w, o[i * 4 + 3]);
        }
      }
    }
  }

  const float inv = 1.f / l;
  float* op = att + ((size_t)b * 2048 + row) * 512 + h * 32;
#pragma unroll
  for (int r8 = 0; r8 < 8; ++r8) {
    f4 v;
    v.x = o[r8 * 4 + 0] * inv;
    v.y = o[r8 * 4 + 1] * inv;
    v.z = o[r8 * 4 + 2] * inv;
    v.w = o[r8 * 4 + 3] * inv;
    *(f4*)(op + r8 * 4) = v;
  }
}

// ---------------------------------------------------------------------------
extern "C" void kernel_launch(void* const* d_in, const int* in_sizes, int n_in,
                              void* d_out, int out_size, void* d_ws, size_t ws_size,
                              hipStream_t stream) {
  const float* hs = (const float*)d_in[0];
  const float* qw = (const float*)d_in[1];
  const float* qb = (const float*)d_in[2];
  const float* kw = (const float*)d_in[3];
  const float* kb = (const float*)d_in[4];
  const float* vw = (const float*)d_in[5];
  const float* vb = (const float*)d_in[6];
  const float* ow = (const float*)d_in[7];
  const float* ob = (const float*)d_in[8];
  float* out = (float*)d_out;
  char* ws = (char*)d_ws;

  // Scratch layout (MB offsets), 86 MB total (ws >= 96 MB proven in R3):
  f16* hsf = (f16*)(ws);                            // 16 MB [8192][1024]
  f16* qf = (f16*)(ws + ((size_t)16 << 20));        // 16 MB [64][2048][64]
  f16* kf = (f16*)(ws + ((size_t)32 << 20));        // 16 MB
  f16* vf = (f16*)(ws + ((size_t)48 << 20));        //  8 MB [64][2048][32]
  float* att = (float*)(ws + ((size_t)56 << 20));   // 16 MB [8192][512] f32
  f16* attf = (f16*)(ws + ((size_t)72 << 20));      //  8 MB [8192][512]
  f16* qwt = (f16*)(ws + ((size_t)80 << 20));       //  2 MB [1024][1024]
  f16* kwt = (f16*)(ws + ((size_t)82 << 20));       //  2 MB
  f16* vwt = (f16*)(ws + ((size_t)84 << 20));       //  1 MB [512][1024]
  f16* owt = (f16*)(ws + ((size_t)85 << 20));       //  1 MB [1024][512]

  cast_f16<<<2048, 256, 0, stream>>>(hs, hsf, 8192 * 1024 / 4);
  transpose_cast<<<dim3(32, 32), 256, 0, stream>>>(qw, qwt, 1024, 1024);
  transpose_cast<<<dim3(32, 32), 256, 0, stream>>>(kw, kwt, 1024, 1024);
  transpose_cast<<<dim3(16, 32), 256, 0, stream>>>(vw, vwt, 1024, 512);
  transpose_cast<<<dim3(32, 16), 256, 0, stream>>>(ow, owt, 512, 1024);

  hgemm<0><<<dim3(8, 64), 256, 0, stream>>>(hsf, qwt, qb, (void*)qf, 1024, 1024);
  hgemm<0><<<dim3(8, 64), 256, 0, stream>>>(hsf, kwt, kb, (void*)kf, 1024, 1024);
  hgemm<2><<<dim3(4, 64), 256, 0, stream>>>(hsf, vwt, vb, (void*)vf, 512, 1024);

  attn_flash<<<dim3(512), 256, 0, stream>>>(qf, kf, vf, att);

  cast_f16<<<2048, 256, 0, stream>>>(att, attf, 8192 * 512 / 4);
  hgemm<3><<<dim3(8, 64), 256, 0, stream>>>(attf, owt, ob, (void*)out, 1024, 512);
}

// Round 5
// 208.272 us; speedup vs baseline: 59.5541x; 4.9985x over previous
//
#include <hip/hip_runtime.h>

typedef _Float16 f16;
typedef __attribute__((ext_vector_type(4))) float f4;
typedef __attribute__((ext_vector_type(4))) _Float16 h4;
typedef __attribute__((ext_vector_type(8))) _Float16 h8;
typedef __attribute__((ext_vector_type(4))) float f32x4;
typedef __attribute__((ext_vector_type(4))) unsigned int u4;

// ---------------------------------------------------------------------------
// Straight cast fp32 -> f16, 4 elems/thread, grid-stride. n4 = n/4.
// ---------------------------------------------------------------------------
__global__ __launch_bounds__(256) void cast_f16(
    const float* __restrict__ in, f16* __restrict__ out, int n4) {
  for (int i = blockIdx.x * 256 + threadIdx.x; i < n4; i += gridDim.x * 256) {
    const f4 v = ((const f4*)in)[i];
    h4 h;
    h.x = (f16)v.x; h.y = (f16)v.y; h.z = (f16)v.z; h.w = (f16)v.w;
    ((h4*)out)[i] = h;
  }
}

// ---------------------------------------------------------------------------
// Transpose + cast: in [R][C] fp32 -> out [C][R] f16. 32x32 LDS tile.
// ---------------------------------------------------------------------------
__global__ __launch_bounds__(256) void transpose_cast(
    const float* __restrict__ in, f16* __restrict__ out, int R, int C) {
  __shared__ float tile[32][33];
  const int t = threadIdx.x, tx = t & 31, ty = t >> 5;
  const int bc = blockIdx.x * 32, br = blockIdx.y * 32;
#pragma unroll
  for (int i = 0; i < 4; ++i)
    tile[ty + i * 8][tx] = in[(size_t)(br + ty + i * 8) * C + bc + tx];
  __syncthreads();
#pragma unroll
  for (int i = 0; i < 4; ++i)
    out[(size_t)(bc + ty + i * 8) * R + br + tx] = (f16)tile[tx][ty + i * 8];
}

// ---------------------------------------------------------------------------
// f16 MFMA GEMM (verified in R4): C = A @ Bt^T + bias.
// Fragment map: A lane l: [row=l&15][k=(l>>4)*8+e]; D reg j: row=(l>>4)*4+j,
// col=l&15.
// MODE 0: f16 out per-head q/k [bh][2048][64]
// MODE 2: f16 out per-head v   [bh][2048][32]
// MODE 3: f32 out row-major [M][N]
// ---------------------------------------------------------------------------
template <int MODE>
__global__ __launch_bounds__(256) void hgemm(
    const f16* __restrict__ A, const f16* __restrict__ Bt,
    const float* __restrict__ bias, void* __restrict__ outp,
    const int N, const int K) {
  __shared__ f16 As[128 * 40];
  __shared__ f16 Bs[128 * 40];
  const int t = threadIdx.x;
  const int lane = t & 63, wave = t >> 6;
  const int wr = wave >> 1, wc = wave & 1;
  const int lrow = lane & 15, lk = lane >> 4;
  const int bm = blockIdx.y * 128, bn = blockIdx.x * 128;

  f32x4 acc[4][4];
#pragma unroll
  for (int i = 0; i < 4; ++i)
#pragma unroll
    for (int j = 0; j < 4; ++j) acc[i][j] = (f32x4)0.f;

  for (int kt = 0; kt < K; kt += 32) {
#pragma unroll
    for (int i = 0; i < 2; ++i) {
      const int ch = t + i * 256;
      const int row = ch >> 2, part = ch & 3;
      *(u4*)&As[row * 40 + part * 8] =
          *(const u4*)(A + (size_t)(bm + row) * K + kt + part * 8);
      *(u4*)&Bs[row * 40 + part * 8] =
          *(const u4*)(Bt + (size_t)(bn + row) * K + kt + part * 8);
    }
    __syncthreads();
    h8 af[4], bf[4];
#pragma unroll
    for (int f = 0; f < 4; ++f) {
      af[f] = *(const h8*)&As[(wr * 64 + f * 16 + lrow) * 40 + lk * 8];
      bf[f] = *(const h8*)&Bs[(wc * 64 + f * 16 + lrow) * 40 + lk * 8];
    }
#pragma unroll
    for (int i = 0; i < 4; ++i)
#pragma unroll
      for (int j = 0; j < 4; ++j)
        acc[i][j] = __builtin_amdgcn_mfma_f32_16x16x32_f16(af[i], bf[j], acc[i][j], 0, 0, 0);
    __syncthreads();
  }

#pragma unroll
  for (int fi = 0; fi < 4; ++fi) {
#pragma unroll
    for (int j = 0; j < 4; ++j) {
      const int grow = bm + wr * 64 + fi * 16 + lk * 4 + j;
      const int bb = grow >> 11, ss = grow & 2047;
#pragma unroll
      for (int fj = 0; fj < 4; ++fj) {
        const int gcol = bn + wc * 64 + fj * 16 + lrow;
        const float g = acc[fi][fj][j] + bias[gcol];
        if (MODE == 0) {
          ((f16*)outp)[((size_t)(bb * 16 + (gcol >> 6)) * 2048 + ss) * 64 + (gcol & 63)] = (f16)g;
        } else if (MODE == 2) {
          ((f16*)outp)[((size_t)(bb * 16 + (gcol >> 5)) * 2048 + ss) * 32 + (gcol & 31)] = (f16)g;
        } else {
          ((float*)outp)[(size_t)grow * N + gcol] = g;
        }
      }
    }
  }
}

// ---------------------------------------------------------------------------
// MFMA causal flash attention.
// qf/kf: [64][2048][64] f16; vf: [64][2048][32] f16; attf: [8192][512] f16.
// Block: 128 queries (4 waves x 32 interleaved), key tiles of 64.
// Wave's queries: q = qbase + fj*64 + w*16 + l15  (fj=0..1).
// S^T = K·Q^T: A=K rows (LDS), B=Q rows (regs). D: col(l&15)=query,
// row((l>>4)*4+j)=key.  Softmax in-register; P -> LDS (A-layout) -> PV with
// V as B-operand assembled from natural [key][r] tile.
// ---------------------------------------------------------------------------
__global__ __launch_bounds__(256) void attn_mfma(
    const f16* __restrict__ qf, const f16* __restrict__ kf,
    const f16* __restrict__ vf, f16* __restrict__ attf) {
  __shared__ f16 Ks[64 * 72];        //  9216 B, K tile [key][d], stride 72
  __shared__ f16 Vs[64 * 36];        //  4608 B, V tile [key][r], stride 36
  __shared__ f16 Ps[4 * 32 * 72];    // 18432 B, per-wave P [qloc][key], stride 72
  const int id = blockIdx.x;
  const int bh = id & 63;
  const int qblk = 15 - (id >> 6);   // heavy-first
  const int qbase = qblk * 128;
  const int t = threadIdx.x;
  const int lane = t & 63, w = t >> 6;
  const int l15 = lane & 15, g = lane >> 4;
  const size_t kvbase = (size_t)bh * 2048;
  f16* Pw = &Ps[w * 32 * 72];

  // Q fragments in registers: qreg[fj][ks], B-operand layout.
  h8 qreg[2][2];
#pragma unroll
  for (int fj = 0; fj < 2; ++fj) {
    const int q = qbase + fj * 64 + w * 16 + l15;
#pragma unroll
    for (int ks = 0; ks < 2; ++ks)
      qreg[fj][ks] = *(const h8*)(qf + (kvbase + q) * 64 + ks * 32 + g * 8);
  }

  f32x4 accO[2][2];  // [fiO(qloc blk)][fr(r blk)]
#pragma unroll
  for (int i = 0; i < 2; ++i)
#pragma unroll
    for (int j = 0; j < 2; ++j) accO[i][j] = (f32x4)0.f;
  float m2[2] = {-1.0e30f, -1.0e30f};
  float lsum[2] = {0.f, 0.f};  // per-lane partial (this lane's key slice)

  const int ntiles = qblk * 2 + 2;
  for (int kt = 0; kt < ntiles; ++kt) {
    const int kbase = kt * 64;
    __syncthreads();
#pragma unroll
    for (int i = 0; i < 2; ++i) {  // stage K 64x64
      const int idx = t + i * 256;
      const int row = idx >> 3, ch = idx & 7;
      *(u4*)&Ks[row * 72 + ch * 8] =
          *(const u4*)(kf + (kvbase + kbase + row) * 64 + ch * 8);
    }
    {  // stage V 64x32
      const int row = t >> 2, ch = t & 3;
      *(u4*)&Vs[row * 36 + ch * 8] =
          *(const u4*)(vf + (kvbase + kbase + row) * 32 + ch * 8);
    }
    __syncthreads();

    // ---- S^T: 16 MFMA ----
    f32x4 accS[4][2];
#pragma unroll
    for (int i = 0; i < 4; ++i)
#pragma unroll
      for (int j = 0; j < 2; ++j) accS[i][j] = (f32x4)0.f;
#pragma unroll
    for (int ks = 0; ks < 2; ++ks) {
#pragma unroll
      for (int fim = 0; fim < 4; ++fim) {
        const h8 af = *(const h8*)&Ks[(fim * 16 + l15) * 72 + ks * 32 + g * 8];
#pragma unroll
        for (int fj = 0; fj < 2; ++fj)
          accS[fim][fj] = __builtin_amdgcn_mfma_f32_16x16x32_f16(af, qreg[fj][ks], accS[fim][fj], 0, 0, 0);
      }
    }

    // ---- online softmax (query = col = l15 per fj) ----
    float corrs[2];
#pragma unroll
    for (int fj = 0; fj < 2; ++fj) {
      const int qg = qbase + fj * 64 + w * 16 + l15;
      float sc[4][4];
      float mc = -1.0e30f;
#pragma unroll
      for (int fim = 0; fim < 4; ++fim)
#pragma unroll
        for (int j = 0; j < 4; ++j) {
          const int key = kbase + fim * 16 + g * 4 + j;
          const float v = accS[fim][fj][j] * 0.125f;
          const float vm = (key <= qg) ? v : -1.0e30f;
          sc[fim][j] = vm;
          mc = fmaxf(mc, vm);
        }
      mc = fmaxf(mc, __shfl_xor(mc, 16));
      mc = fmaxf(mc, __shfl_xor(mc, 32));
      const float mnew = fmaxf(m2[fj], mc);
      const float corr = __expf(m2[fj] - mnew);
      m2[fj] = mnew;
      corrs[fj] = corr;
      float ls = lsum[fj] * corr;
#pragma unroll
      for (int fim = 0; fim < 4; ++fim) {
        h4 hp;
#pragma unroll
        for (int j = 0; j < 4; ++j) {
          const float p = __expf(sc[fim][j] - mnew);  // masked: exp(-1e30)=0
          ls += p;
          hp[j] = (f16)p;
        }
        *(h4*)&Pw[(fj * 16 + l15) * 72 + fim * 16 + g * 4] = hp;
      }
      lsum[fj] = ls;
    }

    // ---- rescale O by corr (O row qloc = fo*16 + g*4 + j -> src lane g*4+j) ----
#pragma unroll
    for (int fo = 0; fo < 2; ++fo) {
#pragma unroll
      for (int j = 0; j < 4; ++j) {
        const float c = __shfl(corrs[fo], g * 4 + j);
        accO[fo][0][j] *= c;
        accO[fo][1][j] *= c;
      }
    }

    // ---- PV: 8 MFMA ----
#pragma unroll
    for (int ks = 0; ks < 2; ++ks) {
      const h8 pa0 = *(const h8*)&Pw[(0 * 16 + l15) * 72 + ks * 32 + g * 8];
      const h8 pa1 = *(const h8*)&Pw[(1 * 16 + l15) * 72 + ks * 32 + g * 8];
#pragma unroll
      for (int fr = 0; fr < 2; ++fr) {
        h8 vb;
#pragma unroll
        for (int e = 0; e < 8; ++e)
          vb[e] = Vs[(ks * 32 + g * 8 + e) * 36 + fr * 16 + l15];
        accO[0][fr] = __builtin_amdgcn_mfma_f32_16x16x32_f16(pa0, vb, accO[0][fr], 0, 0, 0);
        accO[1][fr] = __builtin_amdgcn_mfma_f32_16x16x32_f16(pa1, vb, accO[1][fr], 0, 0, 0);
      }
    }
  }

  // ---- finalize: reduce l across lane groups, scale, store f16 ----
  float inv[2];
#pragma unroll
  for (int fj = 0; fj < 2; ++fj) {
    float ls = lsum[fj];
    ls += __shfl_xor(ls, 16);
    ls += __shfl_xor(ls, 32);
    inv[fj] = 1.f / ls;
  }
  const int b = bh >> 4, h = bh & 15;
#pragma unroll
  for (int fo = 0; fo < 2; ++fo) {
#pragma unroll
    for (int j = 0; j < 4; ++j) {
      const float iv = __shfl(inv[fo], g * 4 + j);
      const int q = qbase + fo * 64 + w * 16 + g * 4 + j;
#pragma unroll
      for (int fr = 0; fr < 2; ++fr) {
        const int r = fr * 16 + l15;
        attf[((size_t)b * 2048 + q) * 512 + h * 32 + r] = (f16)(accO[fo][fr][j] * iv);
      }
    }
  }
}

// ---------------------------------------------------------------------------
extern "C" void kernel_launch(void* const* d_in, const int* in_sizes, int n_in,
                              void* d_out, int out_size, void* d_ws, size_t ws_size,
                              hipStream_t stream) {
  const float* hs = (const float*)d_in[0];
  const float* qw = (const float*)d_in[1];
  const float* qb = (const float*)d_in[2];
  const float* kw = (const float*)d_in[3];
  const float* kb = (const float*)d_in[4];
  const float* vw = (const float*)d_in[5];
  const float* vb = (const float*)d_in[6];
  const float* ow = (const float*)d_in[7];
  const float* ob = (const float*)d_in[8];
  float* out = (float*)d_out;
  char* ws = (char*)d_ws;

  // Scratch (MB offsets), 70 MB total (ws >= 96 MB proven in R3):
  f16* hsf = (f16*)(ws);                        // 16 MB [8192][1024]
  f16* qf = (f16*)(ws + ((size_t)16 << 20));    // 16 MB [64][2048][64]
  f16* kf = (f16*)(ws + ((size_t)32 << 20));    // 16 MB
  f16* vf = (f16*)(ws + ((size_t)48 << 20));    //  8 MB [64][2048][32]
  f16* attf = (f16*)(ws + ((size_t)56 << 20));  //  8 MB [8192][512]
  f16* qwt = (f16*)(ws + ((size_t)64 << 20));   //  2 MB [1024][1024]
  f16* kwt = (f16*)(ws + ((size_t)66 << 20));   //  2 MB
  f16* vwt = (f16*)(ws + ((size_t)68 << 20));   //  1 MB [512][1024]
  f16* owt = (f16*)(ws + ((size_t)69 << 20));   //  1 MB [1024][512]

  cast_f16<<<2048, 256, 0, stream>>>(hs, hsf, 8192 * 1024 / 4);
  transpose_cast<<<dim3(32, 32), 256, 0, stream>>>(qw, qwt, 1024, 1024);
  transpose_cast<<<dim3(32, 32), 256, 0, stream>>>(kw, kwt, 1024, 1024);
  transpose_cast<<<dim3(16, 32), 256, 0, stream>>>(vw, vwt, 1024, 512);
  transpose_cast<<<dim3(32, 16), 256, 0, stream>>>(ow, owt, 512, 1024);

  hgemm<0><<<dim3(8, 64), 256, 0, stream>>>(hsf, qwt, qb, (void*)qf, 1024, 1024);
  hgemm<0><<<dim3(8, 64), 256, 0, stream>>>(hsf, kwt, kb, (void*)kf, 1024, 1024);
  hgemm<2><<<dim3(4, 64), 256, 0, stream>>>(hsf, vwt, vb, (void*)vf, 512, 1024);

  attn_mfma<<<dim3(1024), 256, 0, stream>>>(qf, kf, vf, attf);

  hgemm<3><<<dim3(8, 64), 256, 0, stream>>>(attf, owt, ob, (void*)out, 1024, 512);
}

// Round 6
// 191.129 us; speedup vs baseline: 64.8958x; 1.0897x over previous
//
#include <hip/hip_runtime.h>

typedef _Float16 f16;
typedef __attribute__((ext_vector_type(4))) float f4;
typedef __attribute__((ext_vector_type(4))) _Float16 h4;
typedef __attribute__((ext_vector_type(8))) _Float16 h8;
typedef __attribute__((ext_vector_type(4))) float f32x4;
typedef __attribute__((ext_vector_type(4))) unsigned int u4;

// XOR-swizzle for 128-byte LDS rows (T2): permutes 16B blocks within a row.
#define SWZ(row, colByte) (((row) << 7) + ((colByte) ^ (((row) & 7) << 4)))

// ---------------------------------------------------------------------------
// Transpose + cast: in [R][C] fp32 -> out [C][R] f16. 32x32 LDS tile.
// ---------------------------------------------------------------------------
__global__ __launch_bounds__(256) void transpose_cast(
    const float* __restrict__ in, f16* __restrict__ out, int R, int C) {
  __shared__ float tile[32][33];
  const int t = threadIdx.x, tx = t & 31, ty = t >> 5;
  const int bc = blockIdx.x * 32, br = blockIdx.y * 32;
#pragma unroll
  for (int i = 0; i < 4; ++i)
    tile[ty + i * 8][tx] = in[(size_t)(br + ty + i * 8) * C + bc + tx];
  __syncthreads();
#pragma unroll
  for (int i = 0; i < 4; ++i)
    out[(size_t)(bc + ty + i * 8) * R + br + tx] = (f16)tile[tx][ty + i * 8];
}

// ---------------------------------------------------------------------------
// Fused QKV projection GEMM (A fp32 -> f16 cast in staging).
// A: hs fp32 [8192][1024]. Bt: concat weights f16 [2560][1024] (rows in K).
// Grid x: 20 N-tiles — 0-7 Q, 8-15 K, 16-19 V (per-block uniform region).
// Fragment map (R4/R5-verified): A lane l: [row=l&15][k=(l>>4)*8+e];
// D reg j: row=(l>>4)*4+j, col=l&15.
// ---------------------------------------------------------------------------
__global__ __launch_bounds__(256) void hgemm_qkv(
    const float* __restrict__ A, const f16* __restrict__ Bt,
    const float* __restrict__ qb, const float* __restrict__ kb,
    const float* __restrict__ vb,
    f16* __restrict__ qf, f16* __restrict__ kf, f16* __restrict__ vf) {
  __shared__ f16 As[128 * 40];
  __shared__ f16 Bs[128 * 40];
  const int K = 1024;
  const int t = threadIdx.x;
  const int lane = t & 63, wave = t >> 6;
  const int wr = wave >> 1, wc = wave & 1;
  const int lrow = lane & 15, lk = lane >> 4;
  const int bm = blockIdx.y * 128;
  const int bnT = blockIdx.x;
  const int bn = bnT * 128;

  f32x4 acc[4][4];
#pragma unroll
  for (int i = 0; i < 4; ++i)
#pragma unroll
    for (int j = 0; j < 4; ++j) acc[i][j] = (f32x4)0.f;

  for (int kt = 0; kt < K; kt += 32) {
    {  // stage A fp32 -> f16: 128 rows x 32, 16 floats/thread
      const int row = t >> 1, part = t & 1;
      const float* src = A + (size_t)(bm + row) * K + kt + part * 16;
      const f4 v0 = *(const f4*)(src + 0);
      const f4 v1 = *(const f4*)(src + 4);
      const f4 v2 = *(const f4*)(src + 8);
      const f4 v3 = *(const f4*)(src + 12);
      h8 lo, hi;
      lo[0] = (f16)v0.x; lo[1] = (f16)v0.y; lo[2] = (f16)v0.z; lo[3] = (f16)v0.w;
      lo[4] = (f16)v1.x; lo[5] = (f16)v1.y; lo[6] = (f16)v1.z; lo[7] = (f16)v1.w;
      hi[0] = (f16)v2.x; hi[1] = (f16)v2.y; hi[2] = (f16)v2.z; hi[3] = (f16)v2.w;
      hi[4] = (f16)v3.x; hi[5] = (f16)v3.y; hi[6] = (f16)v3.z; hi[7] = (f16)v3.w;
      *(h8*)&As[row * 40 + part * 16] = lo;
      *(h8*)&As[row * 40 + part * 16 + 8] = hi;
    }
#pragma unroll
    for (int i = 0; i < 2; ++i) {  // stage B f16: 128 rows x 32
      const int ch = t + i * 256;
      const int row = ch >> 2, part = ch & 3;
      *(u4*)&Bs[row * 40 + part * 8] =
          *(const u4*)(Bt + (size_t)(bn + row) * K + kt + part * 8);
    }
    __syncthreads();
    h8 af[4], bf[4];
#pragma unroll
    for (int f = 0; f < 4; ++f) {
      af[f] = *(const h8*)&As[(wr * 64 + f * 16 + lrow) * 40 + lk * 8];
      bf[f] = *(const h8*)&Bs[(wc * 64 + f * 16 + lrow) * 40 + lk * 8];
    }
#pragma unroll
    for (int i = 0; i < 4; ++i)
#pragma unroll
      for (int j = 0; j < 4; ++j)
        acc[i][j] = __builtin_amdgcn_mfma_f32_16x16x32_f16(af[i], bf[j], acc[i][j], 0, 0, 0);
    __syncthreads();
  }

  const float* bias;
  f16* outp;
  int nbase;
  if (bnT < 8) { bias = qb; outp = qf; nbase = 0; }
  else if (bnT < 16) { bias = kb; outp = kf; nbase = 1024; }
  else { bias = vb; outp = vf; nbase = 2048; }

#pragma unroll
  for (int fi = 0; fi < 4; ++fi) {
#pragma unroll
    for (int j = 0; j < 4; ++j) {
      const int grow = bm + wr * 64 + fi * 16 + lk * 4 + j;
      const int bb = grow >> 11, ss = grow & 2047;
#pragma unroll
      for (int fj = 0; fj < 4; ++fj) {
        const int gcol = bn + wc * 64 + fj * 16 + lrow;
        const int nl = gcol - nbase;
        const float g = acc[fi][fj][j] + bias[nl];
        if (bnT < 16) {
          outp[((size_t)(bb * 16 + (nl >> 6)) * 2048 + ss) * 64 + (nl & 63)] = (f16)g;
        } else {
          outp[((size_t)(bb * 16 + (nl >> 5)) * 2048 + ss) * 32 + (nl & 31)] = (f16)g;
        }
      }
    }
  }
}

// ---------------------------------------------------------------------------
// Output projection GEMM (R4/R5-verified structure, A f16): out = attf@owt^T+ob
// ---------------------------------------------------------------------------
__global__ __launch_bounds__(256) void hgemm_out(
    const f16* __restrict__ A, const f16* __restrict__ Bt,
    const float* __restrict__ bias, float* __restrict__ outp,
    const int N, const int K) {
  __shared__ f16 As[128 * 40];
  __shared__ f16 Bs[128 * 40];
  const int t = threadIdx.x;
  const int lane = t & 63, wave = t >> 6;
  const int wr = wave >> 1, wc = wave & 1;
  const int lrow = lane & 15, lk = lane >> 4;
  const int bm = blockIdx.y * 128, bn = blockIdx.x * 128;

  f32x4 acc[4][4];
#pragma unroll
  for (int i = 0; i < 4; ++i)
#pragma unroll
    for (int j = 0; j < 4; ++j) acc[i][j] = (f32x4)0.f;

  for (int kt = 0; kt < K; kt += 32) {
#pragma unroll
    for (int i = 0; i < 2; ++i) {
      const int ch = t + i * 256;
      const int row = ch >> 2, part = ch & 3;
      *(u4*)&As[row * 40 + part * 8] =
          *(const u4*)(A + (size_t)(bm + row) * K + kt + part * 8);
      *(u4*)&Bs[row * 40 + part * 8] =
          *(const u4*)(Bt + (size_t)(bn + row) * K + kt + part * 8);
    }
    __syncthreads();
    h8 af[4], bf[4];
#pragma unroll
    for (int f = 0; f < 4; ++f) {
      af[f] = *(const h8*)&As[(wr * 64 + f * 16 + lrow) * 40 + lk * 8];
      bf[f] = *(const h8*)&Bs[(wc * 64 + f * 16 + lrow) * 40 + lk * 8];
    }
#pragma unroll
    for (int i = 0; i < 4; ++i)
#pragma unroll
      for (int j = 0; j < 4; ++j)
        acc[i][j] = __builtin_amdgcn_mfma_f32_16x16x32_f16(af[i], bf[j], acc[i][j], 0, 0, 0);
    __syncthreads();
  }

#pragma unroll
  for (int fi = 0; fi < 4; ++fi) {
#pragma unroll
    for (int j = 0; j < 4; ++j) {
      const int grow = bm + wr * 64 + fi * 16 + lk * 4 + j;
#pragma unroll
      for (int fj = 0; fj < 4; ++fj) {
        const int gcol = bn + wc * 64 + fj * 16 + lrow;
        outp[(size_t)grow * N + gcol] = acc[fi][fj][j] + bias[gcol];
      }
    }
  }
}

// ---------------------------------------------------------------------------
// MFMA causal flash attention (R5-verified layout + T2 swizzle + V^T tile +
// defer-max). qf/kf: [64][2048][64] f16 (Q pre-scaled here by 0.125);
// vf: [64][2048][32] f16; attf: [8192][512] f16.
// ---------------------------------------------------------------------------
__global__ __launch_bounds__(256) void attn_mfma(
    const f16* __restrict__ qf, const f16* __restrict__ kf,
    const f16* __restrict__ vf, f16* __restrict__ attf) {
  __shared__ f16 Ks[64 * 64];      //  8 KB, [key][d], swizzled 128B rows
  __shared__ f16 VsT[32 * 64];     //  4 KB, [r][key], swizzled
  __shared__ f16 Ps[4 * 32 * 64];  // 16 KB, per-wave [qloc][key], swizzled
  const int id = blockIdx.x;
  const int bh = id & 63;
  const int qblk = 15 - (id >> 6);  // heavy-first
  const int qbase = qblk * 128;
  const int t = threadIdx.x;
  const int lane = t & 63, w = t >> 6;
  const int l15 = lane & 15, g = lane >> 4;
  const size_t kvbase = (size_t)bh * 2048;
  char* Pw = (char*)&Ps[w * 32 * 64];

  // Q fragments, pre-scaled by 1/sqrt(64) (exact pow2 in f16).
  h8 qreg[2][2];
#pragma unroll
  for (int fj = 0; fj < 2; ++fj) {
    const int q = qbase + fj * 64 + w * 16 + l15;
#pragma unroll
    for (int ks = 0; ks < 2; ++ks) {
      h8 raw = *(const h8*)(qf + (kvbase + q) * 64 + ks * 32 + g * 8);
#pragma unroll
      for (int e = 0; e < 8; ++e) raw[e] = raw[e] * (f16)0.125f;
      qreg[fj][ks] = raw;
    }
  }

  f32x4 accO[2][2];
#pragma unroll
  for (int i = 0; i < 2; ++i)
#pragma unroll
    for (int j = 0; j < 2; ++j) accO[i][j] = (f32x4)0.f;
  float m2[2] = {-1.0e30f, -1.0e30f};
  float lsum[2] = {0.f, 0.f};

  const int ntiles = qblk * 2 + 2;
  for (int kt = 0; kt < ntiles; ++kt) {
    const int kbase = kt * 64;
    __syncthreads();
#pragma unroll
    for (int i = 0; i < 2; ++i) {  // stage K 64x64 (swizzled)
      const int idx = t + i * 256;
      const int row = idx >> 3, ch = idx & 7;
      *(u4*)((char*)Ks + SWZ(row, ch * 16)) =
          *(const u4*)(kf + (kvbase + kbase + row) * 64 + ch * 8);
    }
    {  // stage V transposed: VsT[r][key] (swizzled), scalar scatter
      const int key = t >> 2, ch = t & 3;
      const u4 wv = *(const u4*)(vf + (kvbase + kbase + key) * 32 + ch * 8);
      const h8 hv = __builtin_bit_cast(h8, wv);
#pragma unroll
      for (int e = 0; e < 8; ++e) {
        const int row = ch * 8 + e;
        *(f16*)((char*)VsT + SWZ(row, key * 2)) = hv[e];
      }
    }
    __syncthreads();

    // ---- S^T: 16 MFMA ----
    f32x4 accS[4][2];
#pragma unroll
    for (int i = 0; i < 4; ++i)
#pragma unroll
      for (int j = 0; j < 2; ++j) accS[i][j] = (f32x4)0.f;
#pragma unroll
    for (int ks = 0; ks < 2; ++ks) {
#pragma unroll
      for (int fim = 0; fim < 4; ++fim) {
        const h8 af = *(const h8*)((char*)Ks + SWZ(fim * 16 + l15, ks * 64 + g * 16));
#pragma unroll
        for (int fj = 0; fj < 2; ++fj)
          accS[fim][fj] = __builtin_amdgcn_mfma_f32_16x16x32_f16(af, qreg[fj][ks], accS[fim][fj], 0, 0, 0);
      }
    }

    // ---- online softmax (query = col = l15 per fj), defer-max THR=1.5 ----
#pragma unroll
    for (int fj = 0; fj < 2; ++fj) {
      const int qg = qbase + fj * 64 + w * 16 + l15;
      const bool need_mask = (kbase + 63 > qbase + fj * 64 + w * 16);  // wave-uniform
      float sc[4][4];
      float mc = -1.0e30f;
#pragma unroll
      for (int fim = 0; fim < 4; ++fim)
#pragma unroll
        for (int j = 0; j < 4; ++j) {
          float v = accS[fim][fj][j];
          if (need_mask) {
            const int key = kbase + fim * 16 + g * 4 + j;
            v = (key <= qg) ? v : -1.0e30f;
          }
          sc[fim][j] = v;
          mc = fmaxf(mc, v);
        }
      mc = fmaxf(mc, __shfl_xor(mc, 16));
      mc = fmaxf(mc, __shfl_xor(mc, 32));
      if (!__all(mc <= m2[fj] + 1.5f)) {
        const float mnew = fmaxf(m2[fj], mc);
        const float corr = __expf(m2[fj] - mnew);
        m2[fj] = mnew;
        lsum[fj] *= corr;
#pragma unroll
        for (int j = 0; j < 4; ++j) {
          const float c = __shfl(corr, g * 4 + j);
          accO[fj][0][j] *= c;
          accO[fj][1][j] *= c;
        }
      }
      const float mloc = m2[fj];
      float ls = lsum[fj];
#pragma unroll
      for (int fim = 0; fim < 4; ++fim) {
        h4 hp;
#pragma unroll
        for (int j = 0; j < 4; ++j) {
          const float p = __expf(sc[fim][j] - mloc);  // masked -> 0
          ls += p;
          hp[j] = (f16)p;
        }
        *(h4*)(Pw + SWZ(fj * 16 + l15, fim * 32 + g * 8)) = hp;
      }
      lsum[fj] = ls;
    }

    // ---- PV: 8 MFMA, V^T as vector B-operand ----
#pragma unroll
    for (int ks = 0; ks < 2; ++ks) {
      const h8 pa0 = *(const h8*)(Pw + SWZ(l15, ks * 64 + g * 16));
      const h8 pa1 = *(const h8*)(Pw + SWZ(16 + l15, ks * 64 + g * 16));
#pragma unroll
      for (int fr = 0; fr < 2; ++fr) {
        const h8 vb = *(const h8*)((char*)VsT + SWZ(fr * 16 + l15, ks * 64 + g * 16));
        accO[0][fr] = __builtin_amdgcn_mfma_f32_16x16x32_f16(pa0, vb, accO[0][fr], 0, 0, 0);
        accO[1][fr] = __builtin_amdgcn_mfma_f32_16x16x32_f16(pa1, vb, accO[1][fr], 0, 0, 0);
      }
    }
  }

  // ---- finalize ----
  float inv[2];
#pragma unroll
  for (int fj = 0; fj < 2; ++fj) {
    float ls = lsum[fj];
    ls += __shfl_xor(ls, 16);
    ls += __shfl_xor(ls, 32);
    inv[fj] = 1.f / ls;
  }
  const int b = bh >> 4, h = bh & 15;
#pragma unroll
  for (int fo = 0; fo < 2; ++fo) {
#pragma unroll
    for (int j = 0; j < 4; ++j) {
      const float iv = __shfl(inv[fo], g * 4 + j);
      const int q = qbase + fo * 64 + w * 16 + g * 4 + j;
#pragma unroll
      for (int fr = 0; fr < 2; ++fr) {
        const int r = fr * 16 + l15;
        attf[((size_t)b * 2048 + q) * 512 + h * 32 + r] = (f16)(accO[fo][fr][j] * iv);
      }
    }
  }
}

// ---------------------------------------------------------------------------
extern "C" void kernel_launch(void* const* d_in, const int* in_sizes, int n_in,
                              void* d_out, int out_size, void* d_ws, size_t ws_size,
                              hipStream_t stream) {
  const float* hs = (const float*)d_in[0];
  const float* qw = (const float*)d_in[1];
  const float* qb = (const float*)d_in[2];
  const float* kw = (const float*)d_in[3];
  const float* kb = (const float*)d_in[4];
  const float* vw = (const float*)d_in[5];
  const float* vb = (const float*)d_in[6];
  const float* ow = (const float*)d_in[7];
  const float* ob = (const float*)d_in[8];
  float* out = (float*)d_out;
  char* ws = (char*)d_ws;

  // Scratch (MB offsets), 55 MB total (ws >= 96 MB proven in R3):
  f16* qf = (f16*)(ws);                         // 16 MB [64][2048][64]
  f16* kf = (f16*)(ws + ((size_t)16 << 20));    // 16 MB
  f16* vf = (f16*)(ws + ((size_t)32 << 20));    //  8 MB [64][2048][32]
  f16* attf = (f16*)(ws + ((size_t)40 << 20));  //  8 MB [8192][512]
  f16* wqkv = (f16*)(ws + ((size_t)48 << 20));  //  5 MB [2560][1024]
  f16* owt = (f16*)(ws + ((size_t)54 << 20));   //  1 MB [1024][512]

  transpose_cast<<<dim3(32, 32), 256, 0, stream>>>(qw, wqkv, 1024, 1024);
  transpose_cast<<<dim3(32, 32), 256, 0, stream>>>(kw, wqkv + (size_t)1024 * 1024, 1024, 1024);
  transpose_cast<<<dim3(16, 32), 256, 0, stream>>>(vw, wqkv + (size_t)2048 * 1024, 1024, 512);
  transpose_cast<<<dim3(32, 16), 256, 0, stream>>>(ow, owt, 512, 1024);

  hgemm_qkv<<<dim3(20, 64), 256, 0, stream>>>(hs, wqkv, qb, kb, vb, qf, kf, vf);
  attn_mfma<<<dim3(1024), 256, 0, stream>>>(qf, kf, vf, attf);
  hgemm_out<<<dim3(8, 64), 256, 0, stream>>>(attf, owt, ob, out, 1024, 512);
}

// Round 7
// 176.937 us; speedup vs baseline: 70.1009x; 1.0802x over previous
//
#include <hip/hip_runtime.h>

typedef _Float16 f16;
typedef __attribute__((ext_vector_type(4))) float f4;
typedef __attribute__((ext_vector_type(4))) _Float16 h4;
typedef __attribute__((ext_vector_type(8))) _Float16 h8;
typedef __attribute__((ext_vector_type(4))) float f32x4;
typedef __attribute__((ext_vector_type(4))) unsigned int u4;

// XOR-swizzle for 128-byte LDS rows (T2): permutes 16B blocks within a row.
#define SWZ(row, colByte) (((row) << 7) + ((colByte) ^ (((row) & 7) << 4)))

// ---------------------------------------------------------------------------
// Straight cast fp32 -> f16, 4 elems/thread, grid-stride. n4 = n/4.
// ---------------------------------------------------------------------------
__global__ __launch_bounds__(256) void cast_f16(
    const float* __restrict__ in, f16* __restrict__ out, int n4) {
  for (int i = blockIdx.x * 256 + threadIdx.x; i < n4; i += gridDim.x * 256) {
    const f4 v = ((const f4*)in)[i];
    h4 h;
    h.x = (f16)v.x; h.y = (f16)v.y; h.z = (f16)v.z; h.w = (f16)v.w;
    ((h4*)out)[i] = h;
  }
}

// ---------------------------------------------------------------------------
// Transpose + cast: in [R][C] fp32 -> out [C][R] f16. 32x32 LDS tile.
// ---------------------------------------------------------------------------
__global__ __launch_bounds__(256) void transpose_cast(
    const float* __restrict__ in, f16* __restrict__ out, int R, int C) {
  __shared__ float tile[32][33];
  const int t = threadIdx.x, tx = t & 31, ty = t >> 5;
  const int bc = blockIdx.x * 32, br = blockIdx.y * 32;
#pragma unroll
  for (int i = 0; i < 4; ++i)
    tile[ty + i * 8][tx] = in[(size_t)(br + ty + i * 8) * C + bc + tx];
  __syncthreads();
#pragma unroll
  for (int i = 0; i < 4; ++i)
    out[(size_t)(bc + ty + i * 8) * R + br + tx] = (f16)tile[tx][ty + i * 8];
}

// ---------------------------------------------------------------------------
// Fused QKV projection GEMM, f16 A (R4-verified staging + epilogue).
// A: hsf f16 [8192][1024]. Bt: concat weights f16 [2560][1024].
// 1-D grid 1280 = 20 N-tiles x 64 M-tiles; XCD-chunked swizzle: each XCD
// gets 160 consecutive logical ids = 8 full bm-panels (A L2-reuse; B
// re-fetched per XCD = 8 x 5 MB).
// Logical id: bnT = l % 20 (0-7 Q, 8-15 K, 16-19 V), bmT = l / 20.
// ---------------------------------------------------------------------------
__global__ __launch_bounds__(256) void hgemm_qkv(
    const f16* __restrict__ A, const f16* __restrict__ Bt,
    const float* __restrict__ qb, const float* __restrict__ kb,
    const float* __restrict__ vb,
    f16* __restrict__ qf, f16* __restrict__ kf, f16* __restrict__ vf) {
  __shared__ f16 As[128 * 40];
  __shared__ f16 Bs[128 * 40];
  const int K = 1024;
  const int id = blockIdx.x;
  const int swz = (id & 7) * 160 + (id >> 3);  // bijective (1280 % 8 == 0)
  const int bnT = swz % 20;
  const int bm = (swz / 20) * 128;
  const int bn = bnT * 128;
  const int t = threadIdx.x;
  const int lane = t & 63, wave = t >> 6;
  const int wr = wave >> 1, wc = wave & 1;
  const int lrow = lane & 15, lk = lane >> 4;

  f32x4 acc[4][4];
#pragma unroll
  for (int i = 0; i < 4; ++i)
#pragma unroll
    for (int j = 0; j < 4; ++j) acc[i][j] = (f32x4)0.f;

  for (int kt = 0; kt < K; kt += 32) {
#pragma unroll
    for (int i = 0; i < 2; ++i) {
      const int ch = t + i * 256;
      const int row = ch >> 2, part = ch & 3;
      *(u4*)&As[row * 40 + part * 8] =
          *(const u4*)(A + (size_t)(bm + row) * K + kt + part * 8);
      *(u4*)&Bs[row * 40 + part * 8] =
          *(const u4*)(Bt + (size_t)(bn + row) * K + kt + part * 8);
    }
    __syncthreads();
    h8 af[4], bf[4];
#pragma unroll
    for (int f = 0; f < 4; ++f) {
      af[f] = *(const h8*)&As[(wr * 64 + f * 16 + lrow) * 40 + lk * 8];
      bf[f] = *(const h8*)&Bs[(wc * 64 + f * 16 + lrow) * 40 + lk * 8];
    }
#pragma unroll
    for (int i = 0; i < 4; ++i)
#pragma unroll
      for (int j = 0; j < 4; ++j)
        acc[i][j] = __builtin_amdgcn_mfma_f32_16x16x32_f16(af[i], bf[j], acc[i][j], 0, 0, 0);
    __syncthreads();
  }

  const float* bias;
  f16* outp;
  int nbase;
  if (bnT < 8) { bias = qb; outp = qf; nbase = 0; }
  else if (bnT < 16) { bias = kb; outp = kf; nbase = 1024; }
  else { bias = vb; outp = vf; nbase = 2048; }

#pragma unroll
  for (int fi = 0; fi < 4; ++fi) {
#pragma unroll
    for (int j = 0; j < 4; ++j) {
      const int grow = bm + wr * 64 + fi * 16 + lk * 4 + j;
      const int bb = grow >> 11, ss = grow & 2047;
#pragma unroll
      for (int fj = 0; fj < 4; ++fj) {
        const int gcol = bn + wc * 64 + fj * 16 + lrow;
        const int nl = gcol - nbase;
        const float g = acc[fi][fj][j] + bias[nl];
        if (bnT < 16) {
          outp[((size_t)(bb * 16 + (nl >> 6)) * 2048 + ss) * 64 + (nl & 63)] = (f16)g;
        } else {
          outp[((size_t)(bb * 16 + (nl >> 5)) * 2048 + ss) * 32 + (nl & 31)] = (f16)g;
        }
      }
    }
  }
}

// ---------------------------------------------------------------------------
// Output projection GEMM (R4-verified): out = attf @ owt^T + ob. fp32 out.
// 1-D grid 512 = 8 N-tiles x 64 M-tiles, XCD-chunked (chunk = 64 ids).
// ---------------------------------------------------------------------------
__global__ __launch_bounds__(256) void hgemm_out(
    const f16* __restrict__ A, const f16* __restrict__ Bt,
    const float* __restrict__ bias, float* __restrict__ outp,
    const int N, const int K) {
  __shared__ f16 As[128 * 40];
  __shared__ f16 Bs[128 * 40];
  const int id = blockIdx.x;
  const int swz = (id & 7) * 64 + (id >> 3);  // bijective (512 % 8 == 0)
  const int bn = (swz & 7) * 128;
  const int bm = (swz >> 3) * 128;
  const int t = threadIdx.x;
  const int lane = t & 63, wave = t >> 6;
  const int wr = wave >> 1, wc = wave & 1;
  const int lrow = lane & 15, lk = lane >> 4;

  f32x4 acc[4][4];
#pragma unroll
  for (int i = 0; i < 4; ++i)
#pragma unroll
    for (int j = 0; j < 4; ++j) acc[i][j] = (f32x4)0.f;

  for (int kt = 0; kt < K; kt += 32) {
#pragma unroll
    for (int i = 0; i < 2; ++i) {
      const int ch = t + i * 256;
      const int row = ch >> 2, part = ch & 3;
      *(u4*)&As[row * 40 + part * 8] =
          *(const u4*)(A + (size_t)(bm + row) * K + kt + part * 8);
      *(u4*)&Bs[row * 40 + part * 8] =
          *(const u4*)(Bt + (size_t)(bn + row) * K + kt + part * 8);
    }
    __syncthreads();
    h8 af[4], bf[4];
#pragma unroll
    for (int f = 0; f < 4; ++f) {
      af[f] = *(const h8*)&As[(wr * 64 + f * 16 + lrow) * 40 + lk * 8];
      bf[f] = *(const h8*)&Bs[(wc * 64 + f * 16 + lrow) * 40 + lk * 8];
    }
#pragma unroll
    for (int i = 0; i < 4; ++i)
#pragma unroll
      for (int j = 0; j < 4; ++j)
        acc[i][j] = __builtin_amdgcn_mfma_f32_16x16x32_f16(af[i], bf[j], acc[i][j], 0, 0, 0);
    __syncthreads();
  }

#pragma unroll
  for (int fi = 0; fi < 4; ++fi) {
#pragma unroll
    for (int j = 0; j < 4; ++j) {
      const int grow = bm + wr * 64 + fi * 16 + lk * 4 + j;
#pragma unroll
      for (int fj = 0; fj < 4; ++fj) {
        const int gcol = bn + wc * 64 + fj * 16 + lrow;
        outp[(size_t)grow * N + gcol] = acc[fi][fj][j] + bias[gcol];
      }
    }
  }
}

// ---------------------------------------------------------------------------
// MFMA causal flash attention (R6-verified, UNCHANGED).
// qf/kf: [64][2048][64] f16; vf: [64][2048][32] f16; attf: [8192][512] f16.
// ---------------------------------------------------------------------------
__global__ __launch_bounds__(256) void attn_mfma(
    const f16* __restrict__ qf, const f16* __restrict__ kf,
    const f16* __restrict__ vf, f16* __restrict__ attf) {
  __shared__ f16 Ks[64 * 64];      //  8 KB, [key][d], swizzled 128B rows
  __shared__ f16 VsT[32 * 64];     //  4 KB, [r][key], swizzled
  __shared__ f16 Ps[4 * 32 * 64];  // 16 KB, per-wave [qloc][key], swizzled
  const int id = blockIdx.x;
  const int bh = id & 63;
  const int qblk = 15 - (id >> 6);  // heavy-first
  const int qbase = qblk * 128;
  const int t = threadIdx.x;
  const int lane = t & 63, w = t >> 6;
  const int l15 = lane & 15, g = lane >> 4;
  const size_t kvbase = (size_t)bh * 2048;
  char* Pw = (char*)&Ps[w * 32 * 64];

  // Q fragments, pre-scaled by 1/sqrt(64) (exact pow2 in f16).
  h8 qreg[2][2];
#pragma unroll
  for (int fj = 0; fj < 2; ++fj) {
    const int q = qbase + fj * 64 + w * 16 + l15;
#pragma unroll
    for (int ks = 0; ks < 2; ++ks) {
      h8 raw = *(const h8*)(qf + (kvbase + q) * 64 + ks * 32 + g * 8);
#pragma unroll
      for (int e = 0; e < 8; ++e) raw[e] = raw[e] * (f16)0.125f;
      qreg[fj][ks] = raw;
    }
  }

  f32x4 accO[2][2];
#pragma unroll
  for (int i = 0; i < 2; ++i)
#pragma unroll
    for (int j = 0; j < 2; ++j) accO[i][j] = (f32x4)0.f;
  float m2[2] = {-1.0e30f, -1.0e30f};
  float lsum[2] = {0.f, 0.f};

  const int ntiles = qblk * 2 + 2;
  for (int kt = 0; kt < ntiles; ++kt) {
    const int kbase = kt * 64;
    __syncthreads();
#pragma unroll
    for (int i = 0; i < 2; ++i) {  // stage K 64x64 (swizzled)
      const int idx = t + i * 256;
      const int row = idx >> 3, ch = idx & 7;
      *(u4*)((char*)Ks + SWZ(row, ch * 16)) =
          *(const u4*)(kf + (kvbase + kbase + row) * 64 + ch * 8);
    }
    {  // stage V transposed: VsT[r][key] (swizzled), scalar scatter
      const int key = t >> 2, ch = t & 3;
      const u4 wv = *(const u4*)(vf + (kvbase + kbase + key) * 32 + ch * 8);
      const h8 hv = __builtin_bit_cast(h8, wv);
#pragma unroll
      for (int e = 0; e < 8; ++e) {
        const int row = ch * 8 + e;
        *(f16*)((char*)VsT + SWZ(row, key * 2)) = hv[e];
      }
    }
    __syncthreads();

    // ---- S^T: 16 MFMA ----
    f32x4 accS[4][2];
#pragma unroll
    for (int i = 0; i < 4; ++i)
#pragma unroll
      for (int j = 0; j < 2; ++j) accS[i][j] = (f32x4)0.f;
#pragma unroll
    for (int ks = 0; ks < 2; ++ks) {
#pragma unroll
      for (int fim = 0; fim < 4; ++fim) {
        const h8 af = *(const h8*)((char*)Ks + SWZ(fim * 16 + l15, ks * 64 + g * 16));
#pragma unroll
        for (int fj = 0; fj < 2; ++fj)
          accS[fim][fj] = __builtin_amdgcn_mfma_f32_16x16x32_f16(af, qreg[fj][ks], accS[fim][fj], 0, 0, 0);
      }
    }

    // ---- online softmax (query = col = l15 per fj), defer-max THR=1.5 ----
#pragma unroll
    for (int fj = 0; fj < 2; ++fj) {
      const int qg = qbase + fj * 64 + w * 16 + l15;
      const bool need_mask = (kbase + 63 > qbase + fj * 64 + w * 16);  // wave-uniform
      float sc[4][4];
      float mc = -1.0e30f;
#pragma unroll
      for (int fim = 0; fim < 4; ++fim)
#pragma unroll
        for (int j = 0; j < 4; ++j) {
          float v = accS[fim][fj][j];
          if (need_mask) {
            const int key = kbase + fim * 16 + g * 4 + j;
            v = (key <= qg) ? v : -1.0e30f;
          }
          sc[fim][j] = v;
          mc = fmaxf(mc, v);
        }
      mc = fmaxf(mc, __shfl_xor(mc, 16));
      mc = fmaxf(mc, __shfl_xor(mc, 32));
      if (!__all(mc <= m2[fj] + 1.5f)) {
        const float mnew = fmaxf(m2[fj], mc);
        const float corr = __expf(m2[fj] - mnew);
        m2[fj] = mnew;
        lsum[fj] *= corr;
#pragma unroll
        for (int j = 0; j < 4; ++j) {
          const float c = __shfl(corr, g * 4 + j);
          accO[fj][0][j] *= c;
          accO[fj][1][j] *= c;
        }
      }
      const float mloc = m2[fj];
      float ls = lsum[fj];
#pragma unroll
      for (int fim = 0; fim < 4; ++fim) {
        h4 hp;
#pragma unroll
        for (int j = 0; j < 4; ++j) {
          const float p = __expf(sc[fim][j] - mloc);  // masked -> 0
          ls += p;
          hp[j] = (f16)p;
        }
        *(h4*)(Pw + SWZ(fj * 16 + l15, fim * 32 + g * 8)) = hp;
      }
      lsum[fj] = ls;
    }

    // ---- PV: 8 MFMA, V^T as vector B-operand ----
#pragma unroll
    for (int ks = 0; ks < 2; ++ks) {
      const h8 pa0 = *(const h8*)(Pw + SWZ(l15, ks * 64 + g * 16));
      const h8 pa1 = *(const h8*)(Pw + SWZ(16 + l15, ks * 64 + g * 16));
#pragma unroll
      for (int fr = 0; fr < 2; ++fr) {
        const h8 vb = *(const h8*)((char*)VsT + SWZ(fr * 16 + l15, ks * 64 + g * 16));
        accO[0][fr] = __builtin_amdgcn_mfma_f32_16x16x32_f16(pa0, vb, accO[0][fr], 0, 0, 0);
        accO[1][fr] = __builtin_amdgcn_mfma_f32_16x16x32_f16(pa1, vb, accO[1][fr], 0, 0, 0);
      }
    }
  }

  // ---- finalize ----
  float inv[2];
#pragma unroll
  for (int fj = 0; fj < 2; ++fj) {
    float ls = lsum[fj];
    ls += __shfl_xor(ls, 16);
    ls += __shfl_xor(ls, 32);
    inv[fj] = 1.f / ls;
  }
  const int b = bh >> 4, h = bh & 15;
#pragma unroll
  for (int fo = 0; fo < 2; ++fo) {
#pragma unroll
    for (int j = 0; j < 4; ++j) {
      const float iv = __shfl(inv[fo], g * 4 + j);
      const int q = qbase + fo * 64 + w * 16 + g * 4 + j;
#pragma unroll
      for (int fr = 0; fr < 2; ++fr) {
        const int r = fr * 16 + l15;
        attf[((size_t)b * 2048 + q) * 512 + h * 32 + r] = (f16)(accO[fo][fr][j] * iv);
      }
    }
  }
}

// ---------------------------------------------------------------------------
extern "C" void kernel_launch(void* const* d_in, const int* in_sizes, int n_in,
                              void* d_out, int out_size, void* d_ws, size_t ws_size,
                              hipStream_t stream) {
  const float* hs = (const float*)d_in[0];
  const float* qw = (const float*)d_in[1];
  const float* qb = (const float*)d_in[2];
  const float* kw = (const float*)d_in[3];
  const float* kb = (const float*)d_in[4];
  const float* vw = (const float*)d_in[5];
  const float* vb = (const float*)d_in[6];
  const float* ow = (const float*)d_in[7];
  const float* ob = (const float*)d_in[8];
  float* out = (float*)d_out;
  char* ws = (char*)d_ws;

  // Scratch (MB offsets), 72 MB total (ws >= 96 MB proven in R3):
  f16* qf = (f16*)(ws);                         // 16 MB [64][2048][64]
  f16* kf = (f16*)(ws + ((size_t)16 << 20));    // 16 MB
  f16* vf = (f16*)(ws + ((size_t)32 << 20));    //  8 MB [64][2048][32]
  f16* attf = (f16*)(ws + ((size_t)40 << 20));  //  8 MB [8192][512]
  f16* wqkv = (f16*)(ws + ((size_t)48 << 20));  //  5 MB [2560][1024]
  f16* owt = (f16*)(ws + ((size_t)54 << 20));   //  1 MB [1024][512]
  f16* hsf = (f16*)(ws + ((size_t)56 << 20));   // 16 MB [8192][1024]

  cast_f16<<<2048, 256, 0, stream>>>(hs, hsf, 8192 * 1024 / 4);
  transpose_cast<<<dim3(32, 32), 256, 0, stream>>>(qw, wqkv, 1024, 1024);
  transpose_cast<<<dim3(32, 32), 256, 0, stream>>>(kw, wqkv + (size_t)1024 * 1024, 1024, 1024);
  transpose_cast<<<dim3(16, 32), 256, 0, stream>>>(vw, wqkv + (size_t)2048 * 1024, 1024, 512);
  transpose_cast<<<dim3(32, 16), 256, 0, stream>>>(ow, owt, 512, 1024);

  hgemm_qkv<<<dim3(1280), 256, 0, stream>>>(hsf, wqkv, qb, kb, vb, qf, kf, vf);
  attn_mfma<<<dim3(1024), 256, 0, stream>>>(qf, kf, vf, attf);
  hgemm_out<<<dim3(512), 256, 0, stream>>>(attf, owt, ob, out, 1024, 512);
}